// Round 2
// baseline (211.634 us; speedup 1.0000x reference)
//
#include <hip/hip_runtime.h>

// GAE: (B=8192, T=256, A=4, 1) fp32.
// g[t] = d[t] + c[t]*g[t+1], c = GAMMA*LMBDA*(1-term), g[T]=0
// adv = g, ret = g + v. d_out = [adv | ret] flat.
//
// Round-2 structure: ONE WAVE PER SEQUENCE b. Lane = (tc, a) with
// tc=lane>>2 (time chunk, 16 chunks) and a=lane&3 (agent channel).
// Each thread serially composes 16 timesteps of its channel into an
// affine map (D,K); a 4-step shuffle scan over tc stitches chunks;
// pass 2 replays the 16 steps from the exclusive-prefix state.
// No LDS, no __syncthreads, 9 cross-lane ops/thread (was 48 + barrier).

#define GAMMA 0.99f
#define LMBDA 0.95f

constexpr int T = 256;

__global__ __launch_bounds__(256, 4) void gae_scan_kernel(
    const float* __restrict__ reward,
    const float* __restrict__ terminated,
    const float* __restrict__ value,
    const float* __restrict__ next_value,
    float* __restrict__ adv_out,
    float* __restrict__ ret_out)
{
    const int lane = threadIdx.x & 63;
    const int b    = (blockIdx.x * blockDim.x + threadIdx.x) >> 6; // wave id
    const int tc   = lane >> 2;   // time chunk 0..15 (scan order)
    const int a    = lane & 3;    // agent channel

    // Scan order i = 0..255 maps to t = 255-i. Thread (tc) covers
    // i = 16*tc + j, j=0..15  ->  t = 255 - 16*tc - j.
    // Float offset of (b, t, a): b*1024 + 4*t + a.
    const int base = b * 1024 + 1020 - 64 * tc + a;   // j=0 element

    float d[16], c[16], vv[16];
#pragma unroll
    for (int j = 0; j < 16; ++j) {
        const int o = base - 4 * j;
        const float r  = reward[o];
        const float tm = terminated[o];
        const float v  = value[o];
        const float nv = next_value[o];
        const float nd = 1.0f - tm;
        d[j]  = r + GAMMA * nv * nd - v;
        c[j]  = (GAMMA * LMBDA) * nd;
        vv[j] = v;
    }

    // Local chunk composite: state_out = D + K * state_in.
    float D = d[0], K = c[0];
#pragma unroll
    for (int j = 1; j < 16; ++j) { D = d[j] + c[j] * D; K = c[j] * K; }

    // Inclusive shuffle scan over tc (lane stride 4): 4 steps.
#pragma unroll
    for (int s = 1; s < 16; s <<= 1) {
        const float pD = __shfl_up(D, (unsigned)(s * 4), 64);
        const float pK = __shfl_up(K, (unsigned)(s * 4), 64);
        if (tc >= s) { D = D + K * pD; K = K * pK; }
    }

    // Exclusive prefix = state entering this chunk (g before i=16*tc).
    float x = __shfl_up(D, 4u, 64);
    if (tc == 0) x = 0.0f;

    // Pass 2: replay chunk from x, emit outputs.
    float g = x;
#pragma unroll
    for (int j = 0; j < 16; ++j) {
        g = d[j] + c[j] * g;
        const int o = base - 4 * j;
        adv_out[o] = g;
        ret_out[o] = g + vv[j];
    }
}

extern "C" void kernel_launch(void* const* d_in, const int* in_sizes, int n_in,
                              void* d_out, int out_size, void* d_ws, size_t ws_size,
                              hipStream_t stream) {
    const float* reward     = (const float*)d_in[0];
    const float* terminated = (const float*)d_in[1];
    const float* value      = (const float*)d_in[2];
    const float* next_value = (const float*)d_in[3];

    const int B = 8192;
    const int n_elem = B * T * 4;            // 8388608
    float* adv = (float*)d_out;
    float* ret = adv + n_elem;

    // One wave per b: 8192 waves = 2048 blocks of 256 threads.
    const int blocks = (B * 64) / 256;
    gae_scan_kernel<<<blocks, 256, 0, stream>>>(reward, terminated, value,
                                                next_value, adv, ret);
}

// Round 3
// 179.079 us; speedup vs baseline: 1.1818x; 1.1818x over previous
//
#include <hip/hip_runtime.h>

// GAE: (B=8192, T=256, A=4, 1) fp32.
// g[t] = d[t] + c[t]*g[t+1], c = GAMMA*LMBDA*(1-term), g[T]=0
// adv = g, ret = g + v. d_out = [adv | ret] flat.
//
// Round-3 structure: coalesced float4 I/O (thread=timestep) + cheap
// 16-chunk wave scan (thread=(tc,a)) bridged by an LDS transpose.
// One wave per sequence b, 4 sequences per 256-thread block.
// LDS scan layout: 16 rows (j = s%16) x 64 cols, col swizzled by 4*row
// so both access phases are <=2-way bank aliased (free on gfx950).

#define GAMMA 0.99f
#define LMBDA 0.95f

constexpr int T = 256;

__global__ __launch_bounds__(256, 5) void gae_scan_kernel(
    const float* __restrict__ reward,
    const float* __restrict__ terminated,
    const float* __restrict__ value,
    const float* __restrict__ next_value,
    float* __restrict__ adv_out,
    float* __restrict__ ret_out)
{
    __shared__ float bufD[4][16 * 64];   // 16 KB: d, then reused for g
    __shared__ float bufC[4][16 * 64];   // 16 KB: c

    const int w    = threadIdx.x >> 6;   // wave id in block = local sequence
    const int lane = threadIdx.x & 63;
    const int b    = blockIdx.x * 4 + w;

    float* __restrict__ D_ = bufD[w];
    float* __restrict__ C_ = bufC[w];

    // ---- Phase A: coalesced load, compute (d,c), transpose-write to LDS ----
    float4 v4[4];
#pragma unroll
    for (int q = 0; q < 4; ++q) {
        const int f  = 64 * q + lane;       // float4 index = timestep t
        const int gi = b * 256 + f;
        const float4 r  = ((const float4*)reward)[gi];
        const float4 tm = ((const float4*)terminated)[gi];
        const float4 v  = ((const float4*)value)[gi];
        const float4 nv = ((const float4*)next_value)[gi];
        v4[q] = v;

        const int s    = 255 - f;           // scan index (reversed time)
        const int row  = s & 15;            // j within chunk
        const int col  = (4 * (s >> 4) + 4 * row) & 63;  // 4*tc, swizzled
        const int addr = row * 64 + col;    // 4-aligned -> float4 ok

        float4 d4, c4;
        d4.x = r.x + GAMMA * nv.x * (1.0f - tm.x) - v.x;
        d4.y = r.y + GAMMA * nv.y * (1.0f - tm.y) - v.y;
        d4.z = r.z + GAMMA * nv.z * (1.0f - tm.z) - v.z;
        d4.w = r.w + GAMMA * nv.w * (1.0f - tm.w) - v.w;
        c4.x = (GAMMA * LMBDA) * (1.0f - tm.x);
        c4.y = (GAMMA * LMBDA) * (1.0f - tm.y);
        c4.z = (GAMMA * LMBDA) * (1.0f - tm.z);
        c4.w = (GAMMA * LMBDA) * (1.0f - tm.w);
        *((float4*)&D_[addr]) = d4;
        *((float4*)&C_[addr]) = c4;
    }
    __syncthreads();

    // ---- Phase B: per-wave chunked scan. Thread (tc,a) owns 16 steps ----
    const int tc = lane >> 2;    // time chunk 0..15
    const int a  = lane & 3;     // agent channel

    float d[16], c[16];
#pragma unroll
    for (int j = 0; j < 16; ++j) {
        const int col = (4 * tc + 4 * j + a) & 63;
        d[j] = D_[j * 64 + col];
        c[j] = C_[j * 64 + col];
    }

    // Local chunk composite: out = D + K * in.
    float D = d[0], K = c[0];
#pragma unroll
    for (int j = 1; j < 16; ++j) { D = d[j] + c[j] * D; K = c[j] * K; }

    // Inclusive shuffle scan over tc (lane stride 4): 4 steps.
#pragma unroll
    for (int s2 = 1; s2 < 16; s2 <<= 1) {
        const float pD = __shfl_up(D, (unsigned)(4 * s2), 64);
        const float pK = __shfl_up(K, (unsigned)(4 * s2), 64);
        if (tc >= s2) { D = D + K * pD; K = K * pK; }
    }

    // Exclusive prefix = state entering this chunk.
    float x = __shfl_up(D, 4u, 64);
    if (tc == 0) x = 0.0f;

    // Replay chunk, write g back into D-buffer (all reads already in regs).
    float g = x;
#pragma unroll
    for (int j = 0; j < 16; ++j) {
        g = d[j] + c[j] * g;
        const int col = (4 * tc + 4 * j + a) & 63;
        D_[j * 64 + col] = g;
    }
    __syncthreads();

    // ---- Phase C: transpose-read g, coalesced float4 stores ----
#pragma unroll
    for (int q = 0; q < 4; ++q) {
        const int f   = 64 * q + lane;
        const int s   = 255 - f;
        const int row = s & 15;
        const int col = (4 * (s >> 4) + 4 * row) & 63;
        const float4 g4 = *((const float4*)&D_[row * 64 + col]);

        const int gi = b * 256 + f;
        ((float4*)adv_out)[gi] = g4;
        float4 rt;
        rt.x = g4.x + v4[q].x;
        rt.y = g4.y + v4[q].y;
        rt.z = g4.z + v4[q].z;
        rt.w = g4.w + v4[q].w;
        ((float4*)ret_out)[gi] = rt;
    }
}

extern "C" void kernel_launch(void* const* d_in, const int* in_sizes, int n_in,
                              void* d_out, int out_size, void* d_ws, size_t ws_size,
                              hipStream_t stream) {
    const float* reward     = (const float*)d_in[0];
    const float* terminated = (const float*)d_in[1];
    const float* value      = (const float*)d_in[2];
    const float* next_value = (const float*)d_in[3];

    const int B = 8192;
    const int n_elem = B * T * 4;            // 8388608
    float* adv = (float*)d_out;
    float* ret = adv + n_elem;

    // 4 sequences per block -> 2048 blocks of 256 threads.
    gae_scan_kernel<<<B / 4, 256, 0, stream>>>(reward, terminated, value,
                                               next_value, adv, ret);
}